// Round 1
// 187.869 us; speedup vs baseline: 1.0624x; 1.0624x over previous
//
#include <hip/hip_runtime.h>
#include <hip/hip_bf16.h>
#include <stdint.h>

#define S_LEN   2048
#define D_MODEL 1024
#define NH      16
#define DH      64
#define BATCH   2
#define TOKENS  (BATCH * S_LEN)   // 4096

typedef __bf16 bf16;
typedef __bf16 bf16x8 __attribute__((ext_vector_type(8)));
typedef __bf16 b16x4  __attribute__((ext_vector_type(4)));
typedef float  f32x4  __attribute__((ext_vector_type(4)));
typedef float  f32x16 __attribute__((ext_vector_type(16)));
typedef unsigned int uint32;

__device__ __forceinline__ void async_lds16(const void* g, void* l) {
  __builtin_amdgcn_global_load_lds((__attribute__((address_space(1))) void*)g,
                                   (__attribute__((address_space(3))) void*)l,
                                   16, 0, 0);
}

// ---------------------------------------------------------------------------
// fp32 -> bf16 bulk convert (8 elems/thread)
// ---------------------------------------------------------------------------
__global__ __launch_bounds__(256) void convert_kernel(
    const float* __restrict__ src, bf16* __restrict__ dst, int n8) {
  const int i = blockIdx.x * 256 + threadIdx.x;
  if (i >= n8) return;
  const f32x4 a = *(const f32x4*)(src + (size_t)i * 8);
  const f32x4 b = *(const f32x4*)(src + (size_t)i * 8 + 4);
  bf16x8 o;
#pragma unroll
  for (int j = 0; j < 4; j++) { o[j] = (bf16)a[j]; o[j + 4] = (bf16)b[j]; }
  *(bf16x8*)(dst + (size_t)i * 8) = o;
}

// ---------------------------------------------------------------------------
// GEMM core (m97-style): C = A * B^T, bf16, async global->LDS, 128x128, BK=32.
// ---------------------------------------------------------------------------
#define BM 128
#define BN 128
#define BK 32

#define GEMM_CORE(APTR, BPTR, KDIM)                                              \
  __shared__ __align__(16) bf16 As[BM * BK];                                     \
  __shared__ __align__(16) bf16 Bs[BN * BK];                                     \
  const int tid  = threadIdx.x;                                                  \
  const int wave = tid >> 6, lane = tid & 63;                                    \
  const int quad = lane >> 4, l16 = lane & 15;                                   \
  const int m0 = blockIdx.y * BM;                                                \
  const int n0 = blockIdx.x * BN;                                                \
  const int wm = (wave >> 1) * 64, wn = (wave & 1) * 64;                         \
  f32x4 acc[4][4] = {};                                                          \
  const int c0 = tid, c1 = tid + 256;                                            \
  for (int k0 = 0; k0 < (KDIM); k0 += BK) {                                      \
    async_lds16((APTR) + (size_t)(m0 + (c0 >> 2)) * (KDIM) + k0 + (c0 & 3) * 8,  \
                As + c0 * 8);                                                    \
    async_lds16((APTR) + (size_t)(m0 + (c1 >> 2)) * (KDIM) + k0 + (c1 & 3) * 8,  \
                As + c1 * 8);                                                    \
    async_lds16((BPTR) + (size_t)(n0 + (c0 >> 2)) * (KDIM) + k0 + (c0 & 3) * 8,  \
                Bs + c0 * 8);                                                    \
    async_lds16((BPTR) + (size_t)(n0 + (c1 >> 2)) * (KDIM) + k0 + (c1 & 3) * 8,  \
                Bs + c1 * 8);                                                    \
    __syncthreads();                                                             \
    bf16x8 af[4], bfr[4];                                                        \
    _Pragma("unroll") for (int i = 0; i < 4; i++)                                \
        af[i] = *(const bf16x8*)(As + (wm + i * 16 + l16) * BK + quad * 8);      \
    _Pragma("unroll") for (int j = 0; j < 4; j++)                                \
        bfr[j] = *(const bf16x8*)(Bs + (wn + j * 16 + l16) * BK + quad * 8);     \
    _Pragma("unroll") for (int i = 0; i < 4; i++)                                \
      _Pragma("unroll") for (int j = 0; j < 4; j++)                              \
        acc[i][j] = __builtin_amdgcn_mfma_f32_16x16x32_bf16(af[i], bfr[j],       \
                                                            acc[i][j], 0, 0, 0); \
    __syncthreads();                                                             \
  }

// GEMM 1: qkv = xb @ Wqkvb^T -> Q (b,h,s,d, x1/8), K (b,h,s,d), VT (b,h,d,s).
__global__ __launch_bounds__(256) void gemm_qkv_kernel(
    const bf16* __restrict__ X, const bf16* __restrict__ W,
    bf16* __restrict__ Qo, bf16* __restrict__ Ko, bf16* __restrict__ VTo) {
  GEMM_CORE(X, W, D_MODEL)
  const int t = n0 >> 10;  // 0=q 1=k 2=v (uniform per block)
#pragma unroll
  for (int i = 0; i < 4; i++) {
    const int rowb = m0 + wm + i * 16 + quad * 4;   // multiple of 4
    const int b = rowb >> 11, s0 = rowb & 2047;
#pragma unroll
    for (int j = 0; j < 4; j++) {
      const int col = n0 + wn + j * 16 + l16;
      const int h = (col >> 6) & 15, d = col & 63;
      if (t == 2) {
        b16x4 v4;
#pragma unroll
        for (int r = 0; r < 4; r++) v4[r] = (bf16)acc[i][j][r];
        *(b16x4*)(VTo + ((size_t)(b * NH + h) * DH + d) * S_LEN + s0) = v4;
      } else {
#pragma unroll
        for (int r = 0; r < 4; r++) {
          const float v = acc[i][j][r];
          if (t == 0)
            Qo[((size_t)(b * NH + h) * S_LEN + s0 + r) * DH + d] = (bf16)(v * 0.125f);
          else
            Ko[((size_t)(b * NH + h) * S_LEN + s0 + r) * DH + d] = (bf16)v;
        }
      }
    }
  }
}

// GEMM 2: out = AO @ Woutb^T -> d_out fp32
__global__ __launch_bounds__(256) void gemm_out_kernel(
    const bf16* __restrict__ A, const bf16* __restrict__ W,
    float* __restrict__ Out) {
  GEMM_CORE(A, W, D_MODEL)
#pragma unroll
  for (int i = 0; i < 4; i++) {
    const int rowb = m0 + wm + i * 16 + quad * 4;
#pragma unroll
    for (int j = 0; j < 4; j++) {
      const int col = n0 + wn + j * 16 + l16;
#pragma unroll
      for (int r = 0; r < 4; r++)
        Out[(size_t)(rowb + r) * D_MODEL + col] = acc[i][j][r];
    }
  }
}

// ---------------------------------------------------------------------------
// Flash attention v6: 32x32x16 MFMA, 32 q-rows/wave, P in-register via
// cvt_pk_bf16 + permlane32_swap (no P LDS round-trip). 8 waves = 4 q-waves x
// 2 kv-split groups; K/V staged via global_load_lds (linear dest) with XOR
// chunk swizzle applied on the global source and on reads (conflict-free).
// Counted-vmcnt double buffer: loads stay in flight across raw s_barrier.
// LDS 64KB/block -> 2 blocks/CU -> 16 waves/CU.
// Layouts (mfma_f32_32x32x16_bf16, m74/m101-verified C map):
//   C: col=lane&31, row=(r&3)+8*(r>>2)+4*(lane>>5)
//   A: row=lane&31, k=hi*8+j     B: col=lane&31, k=hi*8+j
// S^T = mfma(A=K, B=Q) -> lane holds 32 P-rows for one q-col.
// O^T = mfma(A=V^T, B=P^T); P^T B-frags built by swapping packed bf16 pairs
// across the lane^32 boundary (derivation: hi=0 owns keys 4hi+{0..3,8..11,..}).
// ---------------------------------------------------------------------------
__global__ __launch_bounds__(512, 4) void attn_kernel(
    const bf16* __restrict__ Q, const bf16* __restrict__ K,
    const bf16* __restrict__ VT, bf16* __restrict__ AO) {
  __shared__ __align__(16) bf16 smem[2][2][2 * 64 * 64];  // [kv-grp][buf][K|V] 64KB

  const int tid  = threadIdx.x;
  const int lane = tid & 63;
  const int wave = tid >> 6;
  const int g    = wave >> 2;      // kv-split group (0/1)
  const int qw   = wave & 3;       // q-wave within group
  const int l31  = lane & 31;
  const int hi   = lane >> 5;
  const int sw   = l31 & 7;        // read-side XOR swizzle key

  // XCD-bijective remap: 64 consecutive logical blocks (4 heads) per XCD
  const int bid = (blockIdx.x & 7) * 64 + (blockIdx.x >> 3);
  const int qb  = bid & 15;
  const int bh  = bid >> 4;

  const bf16* qp = Q  + ((size_t)bh * S_LEN + qb * 128 + qw * 32 + l31) * DH;
  const bf16* kp = K  + (size_t)bh * S_LEN * DH;
  const bf16* vp = VT + (size_t)bh * DH * S_LEN;

  // Q B-fragments: col=q=l31 (fixed/lane), k-rows = dk*16 + hi*8 + j
  bf16x8 qf[4];
#pragma unroll
  for (int dk = 0; dk < 4; dk++)
    qf[dk] = *(const bf16x8*)(qp + dk * 16 + hi * 8);

  // staging: 256 threads/group move K(8KB)+V(8KB) as 4x16B chunks/thread.
  // LDS dest is linear (chunk id = gtid, gtid+256); global src pre-swizzled
  // so that read-side "chunk c of row r lives at c^(r&7)" holds (rule 21).
  const int gtid = tid & 255;
  const int cid0 = gtid, cid1 = gtid + 256;
  const int r0 = cid0 >> 3, c0 = (cid0 & 7) ^ (r0 & 7);
  const int r1 = cid1 >> 3, c1 = (cid1 & 7) ^ (r1 & 7);
  const bf16* ka0 = kp + (size_t)(g * 64 + r0) * DH + c0 * 8;
  const bf16* ka1 = kp + (size_t)(g * 64 + r1) * DH + c1 * 8;
  const bf16* va0 = vp + (size_t)r0 * S_LEN + g * 64 + c0 * 8;
  const bf16* va1 = vp + (size_t)r1 * S_LEN + g * 64 + c1 * 8;
  const int ld0 = cid0 * 8, ld1 = cid1 * 8;   // LDS element offsets

  f32x16 oT[2] = {};
  float lsum = 0.f;

  bf16* sg = &smem[g][0][0];   // group's buf0; buf1 at +8192 elems

#define STAGE(B)                                                                 \
  {                                                                              \
    bf16* s = sg + (B) * (2 * 64 * 64);                                          \
    async_lds16(ka0, s + ld0);                                                   \
    async_lds16(ka1, s + ld1);                                                   \
    async_lds16(va0, s + 4096 + ld0);                                            \
    async_lds16(va1, s + 4096 + ld1);                                            \
    ka0 += 8192; ka1 += 8192; va0 += 128; va1 += 128;                            \
  }

  STAGE(0)

  for (int t = 0; t < 16; t++) {
    const int cur = t & 1;
    if (t < 15) {
      STAGE(cur ^ 1)
      asm volatile("s_waitcnt vmcnt(4)" ::: "memory");   // cur tile landed
    } else {
      asm volatile("s_waitcnt vmcnt(0)" ::: "memory");
    }
    __builtin_amdgcn_s_barrier();
    __builtin_amdgcn_s_setprio(1);

    const bf16* sb = sg + cur * (2 * 64 * 64);

    // S^T[key][q]: 2 key-tiles x 4 k-slots, K A-frags from swizzled LDS
    f32x16 st[2] = {};
#pragma unroll
    for (int kt = 0; kt < 2; kt++)
#pragma unroll
      for (int dk = 0; dk < 4; dk++) {
        const bf16x8 kf = *(const bf16x8*)(sb + (kt * 32 + l31) * 64 +
                                           (((dk * 2 + hi) ^ sw) * 8));
        st[kt] = __builtin_amdgcn_mfma_f32_32x32x16_bf16(kf, qf[dk], st[kt], 0, 0, 0);
      }

    // exp -> pack bf16 pairs -> swap across lane^32 -> PV (P never touches LDS)
#pragma unroll
    for (int kt = 0; kt < 2; kt++)
#pragma unroll
      for (int half = 0; half < 2; half++) {
        float e[8];
#pragma unroll
        for (int r = 0; r < 8; r++) e[r] = __expf(st[kt][half * 8 + r]);
        lsum += ((e[0] + e[1]) + (e[2] + e[3])) + ((e[4] + e[5]) + (e[6] + e[7]));
        uint32 a0, a1, b0, b1;
        asm("v_cvt_pk_bf16_f32 %0, %1, %2" : "=v"(a0) : "v"(e[0]), "v"(e[1]));
        asm("v_cvt_pk_bf16_f32 %0, %1, %2" : "=v"(a1) : "v"(e[2]), "v"(e[3]));
        asm("v_cvt_pk_bf16_f32 %0, %1, %2" : "=v"(b0) : "v"(e[4]), "v"(e[5]));
        asm("v_cvt_pk_bf16_f32 %0, %1, %2" : "=v"(b1) : "v"(e[6]), "v"(e[7]));
        asm("v_permlane32_swap_b32 %0, %1" : "+v"(a0), "+v"(b0));
        asm("v_permlane32_swap_b32 %0, %1" : "+v"(a1), "+v"(b1));
        union { uint32 u[4]; bf16x8 v; } pf;
        pf.u[0] = a0; pf.u[1] = a1; pf.u[2] = b0; pf.u[3] = b1;
        const int ks = kt * 2 + half;
#pragma unroll
        for (int dt = 0; dt < 2; dt++) {
          const bf16x8 vf = *(const bf16x8*)(sb + 4096 + (dt * 32 + l31) * 64 +
                                             (((ks * 2 + hi) ^ sw) * 8));
          oT[dt] = __builtin_amdgcn_mfma_f32_32x32x16_bf16(vf, pf.v, oT[dt], 0, 0, 0);
        }
      }

    __builtin_amdgcn_s_setprio(0);
    asm volatile("s_waitcnt lgkmcnt(0)" ::: "memory");   // reads of cur done
    __builtin_amdgcn_s_barrier();                        // before cur is restaged
  }
#undef STAGE

  // column total: partner lane (lane^32) holds the other 32 key-rows
  lsum += __shfl_xor(lsum, 32);

  // kv-split merge through LDS (group 1 -> group 0), swizzled to avoid
  // same-bank columns; buffers are dead after the loop.
  float* mO = (float*)&smem[0][0][0];            // 32 KB: 256 rows x 128 B
  float* mL = mO + 4 * 64 * 32;                  // 1 KB
  const int mrow = qw * 64 + lane;
  if (g == 1) {
#pragma unroll
    for (int j = 0; j < 8; j++) {
      const int dt = j >> 2, rb = (j & 3) * 4;
      f32x4 c = { oT[dt][rb], oT[dt][rb + 1], oT[dt][rb + 2], oT[dt][rb + 3] };
      *(f32x4*)((char*)mO + mrow * 128 + ((j ^ (lane & 7)) * 16)) = c;
    }
    mL[mrow] = lsum;
  }
  __syncthreads();
  if (g == 0) {
#pragma unroll
    for (int j = 0; j < 8; j++) {
      const int dt = j >> 2, rb = (j & 3) * 4;
      const f32x4 c = *(const f32x4*)((char*)mO + mrow * 128 + ((j ^ (lane & 7)) * 16));
#pragma unroll
      for (int rr = 0; rr < 4; rr++) oT[dt][rb + rr] += c[rr];
    }
    lsum += mL[mrow];
    const float inv = 1.0f / (lsum + 1e-6f);
    const int b = bh >> 4, h = bh & 15;
    const int srow = qb * 128 + qw * 32 + l31;   // q = col = l31 per lane
    const size_t base = (size_t)(b * S_LEN + srow) * D_MODEL + h * DH;
#pragma unroll
    for (int dt = 0; dt < 2; dt++)
#pragma unroll
      for (int rg = 0; rg < 4; rg++) {
        b16x4 o4;
#pragma unroll
        for (int rr = 0; rr < 4; rr++) o4[rr] = (bf16)(oT[dt][rg * 4 + rr] * inv);
        *(b16x4*)(AO + base + dt * 32 + rg * 8 + hi * 4) = o4;
      }
  }
}

extern "C" void kernel_launch(void* const* d_in, const int* in_sizes, int n_in,
                              void* d_out, int out_size, void* d_ws, size_t ws_size,
                              hipStream_t stream) {
  const float* x    = (const float*)d_in[0];
  const float* wqkv = (const float*)d_in[1];
  const float* wout = (const float*)d_in[2];
  float* out = (float*)d_out;

  // ws (32 MB): [Q 8MB][K 8MB][VT 8MB][xb 8MB -> AO after gemm_qkv]
  bf16* Q  = (bf16*)d_ws;
  bf16* K  = Q  + (size_t)TOKENS * D_MODEL;
  bf16* VT = K  + (size_t)TOKENS * D_MODEL;
  bf16* xb = VT + (size_t)TOKENS * D_MODEL;
  bf16* AO = xb;                       // xb dead after gemm_qkv
  bf16* wqkvb = (bf16*)d_out;          // d_out dead until gemm_out
  bf16* woutb = Q;                     // Q dead after attn

  convert_kernel<<<dim3(TOKENS * D_MODEL / (256 * 8)), dim3(256), 0, stream>>>(
      x, xb, TOKENS * D_MODEL / 8);
  convert_kernel<<<dim3(3 * D_MODEL * D_MODEL / (256 * 8)), dim3(256), 0, stream>>>(
      wqkv, wqkvb, 3 * D_MODEL * D_MODEL / 8);

  gemm_qkv_kernel<<<dim3(3 * D_MODEL / BN, TOKENS / BM), dim3(256), 0, stream>>>(
      xb, wqkvb, Q, K, VT);

  attn_kernel<<<dim3(BATCH * NH * (S_LEN / 128)), dim3(512), 0, stream>>>(Q, K, VT, AO);

  convert_kernel<<<dim3(D_MODEL * D_MODEL / (256 * 8)), dim3(256), 0, stream>>>(
      wout, woutb, D_MODEL * D_MODEL / 8);

  gemm_out_kernel<<<dim3(D_MODEL / BN, TOKENS / BM), dim3(256), 0, stream>>>(
      AO, woutb, out);
}

// Round 2
// 186.607 us; speedup vs baseline: 1.0696x; 1.0068x over previous
//
#include <hip/hip_runtime.h>
#include <hip/hip_bf16.h>
#include <stdint.h>

#define S_LEN   2048
#define D_MODEL 1024
#define NH      16
#define DH      64
#define BATCH   2
#define TOKENS  (BATCH * S_LEN)   // 4096

typedef __bf16 bf16;
typedef __bf16 bf16x8 __attribute__((ext_vector_type(8)));
typedef __bf16 b16x4  __attribute__((ext_vector_type(4)));
typedef float  f32x4  __attribute__((ext_vector_type(4)));
typedef float  f32x16 __attribute__((ext_vector_type(16)));
typedef unsigned int uint32;

__device__ __forceinline__ void async_lds16(const void* g, void* l) {
  __builtin_amdgcn_global_load_lds((__attribute__((address_space(1))) void*)g,
                                   (__attribute__((address_space(3))) void*)l,
                                   16, 0, 0);
}

// ---------------------------------------------------------------------------
// fp32 -> bf16 bulk convert (8 elems/thread)
// ---------------------------------------------------------------------------
__global__ __launch_bounds__(256) void convert_kernel(
    const float* __restrict__ src, bf16* __restrict__ dst, int n8) {
  const int i = blockIdx.x * 256 + threadIdx.x;
  if (i >= n8) return;
  const f32x4 a = *(const f32x4*)(src + (size_t)i * 8);
  const f32x4 b = *(const f32x4*)(src + (size_t)i * 8 + 4);
  bf16x8 o;
#pragma unroll
  for (int j = 0; j < 4; j++) { o[j] = (bf16)a[j]; o[j + 4] = (bf16)b[j]; }
  *(bf16x8*)(dst + (size_t)i * 8) = o;
}

// ---------------------------------------------------------------------------
// GEMM core (m97-style): C = A * B^T, bf16, async global->LDS, 128x128, BK=32.
// ---------------------------------------------------------------------------
#define BM 128
#define BN 128
#define BK 32

#define GEMM_CORE(APTR, BPTR, KDIM)                                              \
  __shared__ __align__(16) bf16 As[BM * BK];                                     \
  __shared__ __align__(16) bf16 Bs[BN * BK];                                     \
  const int tid  = threadIdx.x;                                                  \
  const int wave = tid >> 6, lane = tid & 63;                                    \
  const int quad = lane >> 4, l16 = lane & 15;                                   \
  const int m0 = blockIdx.y * BM;                                                \
  const int n0 = blockIdx.x * BN;                                                \
  const int wm = (wave >> 1) * 64, wn = (wave & 1) * 64;                         \
  f32x4 acc[4][4] = {};                                                          \
  const int c0 = tid, c1 = tid + 256;                                            \
  for (int k0 = 0; k0 < (KDIM); k0 += BK) {                                      \
    async_lds16((APTR) + (size_t)(m0 + (c0 >> 2)) * (KDIM) + k0 + (c0 & 3) * 8,  \
                As + c0 * 8);                                                    \
    async_lds16((APTR) + (size_t)(m0 + (c1 >> 2)) * (KDIM) + k0 + (c1 & 3) * 8,  \
                As + c1 * 8);                                                    \
    async_lds16((BPTR) + (size_t)(n0 + (c0 >> 2)) * (KDIM) + k0 + (c0 & 3) * 8,  \
                Bs + c0 * 8);                                                    \
    async_lds16((BPTR) + (size_t)(n0 + (c1 >> 2)) * (KDIM) + k0 + (c1 & 3) * 8,  \
                Bs + c1 * 8);                                                    \
    __syncthreads();                                                             \
    bf16x8 af[4], bfr[4];                                                        \
    _Pragma("unroll") for (int i = 0; i < 4; i++)                                \
        af[i] = *(const bf16x8*)(As + (wm + i * 16 + l16) * BK + quad * 8);      \
    _Pragma("unroll") for (int j = 0; j < 4; j++)                                \
        bfr[j] = *(const bf16x8*)(Bs + (wn + j * 16 + l16) * BK + quad * 8);     \
    _Pragma("unroll") for (int i = 0; i < 4; i++)                                \
      _Pragma("unroll") for (int j = 0; j < 4; j++)                              \
        acc[i][j] = __builtin_amdgcn_mfma_f32_16x16x32_bf16(af[i], bfr[j],       \
                                                            acc[i][j], 0, 0, 0); \
    __syncthreads();                                                             \
  }

// GEMM 1: qkv = xb @ Wqkvb^T -> Q (b,h,s,d, x1/8), K (b,h,s,d), VT (b,h,d,s).
__global__ __launch_bounds__(256) void gemm_qkv_kernel(
    const bf16* __restrict__ X, const bf16* __restrict__ W,
    bf16* __restrict__ Qo, bf16* __restrict__ Ko, bf16* __restrict__ VTo) {
  GEMM_CORE(X, W, D_MODEL)
  const int t = n0 >> 10;  // 0=q 1=k 2=v (uniform per block)
#pragma unroll
  for (int i = 0; i < 4; i++) {
    const int rowb = m0 + wm + i * 16 + quad * 4;   // multiple of 4
    const int b = rowb >> 11, s0 = rowb & 2047;
#pragma unroll
    for (int j = 0; j < 4; j++) {
      const int col = n0 + wn + j * 16 + l16;
      const int h = (col >> 6) & 15, d = col & 63;
      if (t == 2) {
        b16x4 v4;
#pragma unroll
        for (int r = 0; r < 4; r++) v4[r] = (bf16)acc[i][j][r];
        *(b16x4*)(VTo + ((size_t)(b * NH + h) * DH + d) * S_LEN + s0) = v4;
      } else {
#pragma unroll
        for (int r = 0; r < 4; r++) {
          const float v = acc[i][j][r];
          if (t == 0)
            Qo[((size_t)(b * NH + h) * S_LEN + s0 + r) * DH + d] = (bf16)(v * 0.125f);
          else
            Ko[((size_t)(b * NH + h) * S_LEN + s0 + r) * DH + d] = (bf16)v;
        }
      }
    }
  }
}

// GEMM 2: out = AO @ Woutb^T -> d_out fp32
__global__ __launch_bounds__(256) void gemm_out_kernel(
    const bf16* __restrict__ A, const bf16* __restrict__ W,
    float* __restrict__ Out) {
  GEMM_CORE(A, W, D_MODEL)
#pragma unroll
  for (int i = 0; i < 4; i++) {
    const int rowb = m0 + wm + i * 16 + quad * 4;
#pragma unroll
    for (int j = 0; j < 4; j++) {
      const int col = n0 + wn + j * 16 + l16;
#pragma unroll
      for (int r = 0; r < 4; r++)
        Out[(size_t)(rowb + r) * D_MODEL + col] = acc[i][j][r];
    }
  }
}

// ---------------------------------------------------------------------------
// Flash attention v7: 64 q-rows/wave (two 32-q halves share every K/V LDS
// read -> ds_read:MFMA ratio 1:2, halving LDS-pipe pressure vs v6).
// 8 waves = 2 kv-groups x 4 q-waves; block = 256 q-rows; grid = 256 blocks
// (1/CU). VGPR ~230 -> 2 waves/SIMD (enforced via __launch_bounds__(512,2)).
// P in-register via cvt_pk_bf16 + permlane32_swap; K/V staged by
// global_load_lds (linear dest) with XOR chunk swizzle on global src + reads.
// Counted-vmcnt double buffer; kv-split merged in two 32KB LDS rounds.
// Layouts (mfma_f32_32x32x16_bf16, m74/m101-verified C map):
//   C: col=lane&31, row=(r&3)+8*(r>>2)+4*(lane>>5)
//   A: row=lane&31, k=hi*8+j     B: col=lane&31, k=hi*8+j
// ---------------------------------------------------------------------------
__global__ __launch_bounds__(512, 2) void attn_kernel(
    const bf16* __restrict__ Q, const bf16* __restrict__ K,
    const bf16* __restrict__ VT, bf16* __restrict__ AO) {
  __shared__ __align__(16) bf16 smem[2][2][2 * 64 * 64];  // [kv-grp][buf][K|V] 64KB

  const int tid  = threadIdx.x;
  const int lane = tid & 63;
  const int wave = tid >> 6;
  const int g    = wave >> 2;      // kv-split group (0/1)
  const int qw   = wave & 3;       // q-wave within group
  const int l31  = lane & 31;
  const int hi   = lane >> 5;
  const int sw   = l31 & 7;        // read-side XOR swizzle key

  // XCD-bijective remap: 32 consecutive logical blocks (4 heads) per XCD
  const int bid = (blockIdx.x & 7) * 32 + (blockIdx.x >> 3);
  const int qb  = bid & 7;         // 2048/256
  const int bh  = bid >> 3;        // 0..31

  const bf16* qp = Q  + ((size_t)bh * S_LEN + qb * 256 + qw * 64 + l31) * DH;
  const bf16* kp = K  + (size_t)bh * S_LEN * DH;
  const bf16* vp = VT + (size_t)bh * DH * S_LEN;

  // Q B-fragments for both q-halves: col=q=l31, k-rows = dk*16 + hi*8 + j
  bf16x8 qf0[4], qf1[4];
#pragma unroll
  for (int dk = 0; dk < 4; dk++) {
    qf0[dk] = *(const bf16x8*)(qp + dk * 16 + hi * 8);
    qf1[dk] = *(const bf16x8*)(qp + 32 * DH + dk * 16 + hi * 8);
  }

  // staging: 256 threads/group move K(8KB)+V(8KB) as 4x16B chunks/thread.
  // LDS dest linear; global src pre-swizzled so read-side
  // "chunk c of row r lives at c^(r&7)" holds (rule 21).
  const int gtid = tid & 255;
  const int cid0 = gtid, cid1 = gtid + 256;
  const int r0 = cid0 >> 3, c0 = (cid0 & 7) ^ (r0 & 7);
  const int r1 = cid1 >> 3, c1 = (cid1 & 7) ^ (r1 & 7);
  const bf16* ka0 = kp + (size_t)(g * 64 + r0) * DH + c0 * 8;
  const bf16* ka1 = kp + (size_t)(g * 64 + r1) * DH + c1 * 8;
  const bf16* va0 = vp + (size_t)r0 * S_LEN + g * 64 + c0 * 8;
  const bf16* va1 = vp + (size_t)r1 * S_LEN + g * 64 + c1 * 8;
  const int ld0 = cid0 * 8, ld1 = cid1 * 8;   // LDS element offsets

  f32x16 oT0[2] = {}, oT1[2] = {};
  float lsum0 = 0.f, lsum1 = 0.f;

  bf16* sg = &smem[g][0][0];   // group's buf0; buf1 at +8192 elems

#define STAGE(B)                                                                 \
  {                                                                              \
    bf16* s = sg + (B) * (2 * 64 * 64);                                          \
    async_lds16(ka0, s + ld0);                                                   \
    async_lds16(ka1, s + ld1);                                                   \
    async_lds16(va0, s + 4096 + ld0);                                            \
    async_lds16(va1, s + 4096 + ld1);                                            \
    ka0 += 8192; ka1 += 8192; va0 += 128; va1 += 128;                            \
  }

  STAGE(0)

  for (int t = 0; t < 16; t++) {
    const int cur = t & 1;
    if (t < 15) {
      STAGE(cur ^ 1)
      asm volatile("s_waitcnt vmcnt(4)" ::: "memory");   // cur tile landed
    } else {
      asm volatile("s_waitcnt vmcnt(0)" ::: "memory");
    }
    __builtin_amdgcn_s_barrier();
    __builtin_amdgcn_s_setprio(1);

    const bf16* sb = sg + cur * (2 * 64 * 64);

    // S^T[key][q]: each K-fragment read feeds BOTH q-halves (2 MFMAs/read)
    f32x16 st0[2] = {}, st1[2] = {};
#pragma unroll
    for (int kt = 0; kt < 2; kt++)
#pragma unroll
      for (int dk = 0; dk < 4; dk++) {
        const bf16x8 kf = *(const bf16x8*)(sb + (kt * 32 + l31) * 64 +
                                           (((dk * 2 + hi) ^ sw) * 8));
        st0[kt] = __builtin_amdgcn_mfma_f32_32x32x16_bf16(kf, qf0[dk], st0[kt], 0, 0, 0);
        st1[kt] = __builtin_amdgcn_mfma_f32_32x32x16_bf16(kf, qf1[dk], st1[kt], 0, 0, 0);
      }

    // exp -> pack -> permlane swap -> PV; each V-fragment read feeds both halves
#pragma unroll
    for (int kt = 0; kt < 2; kt++)
#pragma unroll
      for (int hk = 0; hk < 2; hk++) {
        const int ks = kt * 2 + hk;
        float e0[8], e1[8];
#pragma unroll
        for (int r = 0; r < 8; r++) e0[r] = __expf(st0[kt][hk * 8 + r]);
#pragma unroll
        for (int r = 0; r < 8; r++) e1[r] = __expf(st1[kt][hk * 8 + r]);
        lsum0 += ((e0[0] + e0[1]) + (e0[2] + e0[3])) + ((e0[4] + e0[5]) + (e0[6] + e0[7]));
        lsum1 += ((e1[0] + e1[1]) + (e1[2] + e1[3])) + ((e1[4] + e1[5]) + (e1[6] + e1[7]));
        uint32 p00, p01, p02, p03, p10, p11, p12, p13;
        asm("v_cvt_pk_bf16_f32 %0, %1, %2" : "=v"(p00) : "v"(e0[0]), "v"(e0[1]));
        asm("v_cvt_pk_bf16_f32 %0, %1, %2" : "=v"(p01) : "v"(e0[2]), "v"(e0[3]));
        asm("v_cvt_pk_bf16_f32 %0, %1, %2" : "=v"(p02) : "v"(e0[4]), "v"(e0[5]));
        asm("v_cvt_pk_bf16_f32 %0, %1, %2" : "=v"(p03) : "v"(e0[6]), "v"(e0[7]));
        asm("v_cvt_pk_bf16_f32 %0, %1, %2" : "=v"(p10) : "v"(e1[0]), "v"(e1[1]));
        asm("v_cvt_pk_bf16_f32 %0, %1, %2" : "=v"(p11) : "v"(e1[2]), "v"(e1[3]));
        asm("v_cvt_pk_bf16_f32 %0, %1, %2" : "=v"(p12) : "v"(e1[4]), "v"(e1[5]));
        asm("v_cvt_pk_bf16_f32 %0, %1, %2" : "=v"(p13) : "v"(e1[6]), "v"(e1[7]));
        asm("v_permlane32_swap_b32 %0, %1" : "+v"(p00), "+v"(p02));
        asm("v_permlane32_swap_b32 %0, %1" : "+v"(p01), "+v"(p03));
        asm("v_permlane32_swap_b32 %0, %1" : "+v"(p10), "+v"(p12));
        asm("v_permlane32_swap_b32 %0, %1" : "+v"(p11), "+v"(p13));
        union { uint32 u[4]; bf16x8 v; } pf0, pf1;
        pf0.u[0] = p00; pf0.u[1] = p01; pf0.u[2] = p02; pf0.u[3] = p03;
        pf1.u[0] = p10; pf1.u[1] = p11; pf1.u[2] = p12; pf1.u[3] = p13;
#pragma unroll
        for (int dt = 0; dt < 2; dt++) {
          const bf16x8 vf = *(const bf16x8*)(sb + 4096 + (dt * 32 + l31) * 64 +
                                             (((ks * 2 + hi) ^ sw) * 8));
          oT0[dt] = __builtin_amdgcn_mfma_f32_32x32x16_bf16(vf, pf0.v, oT0[dt], 0, 0, 0);
          oT1[dt] = __builtin_amdgcn_mfma_f32_32x32x16_bf16(vf, pf1.v, oT1[dt], 0, 0, 0);
        }
      }

    __builtin_amdgcn_s_setprio(0);
    asm volatile("s_waitcnt lgkmcnt(0)" ::: "memory");   // reads of cur done
    __builtin_amdgcn_s_barrier();                        // before cur is restaged
  }
#undef STAGE

  // column total: partner lane (lane^32) holds the other 32 key-rows
  lsum0 += __shfl_xor(lsum0, 32);
  lsum1 += __shfl_xor(lsum1, 32);

  // kv-split merge (group 1 -> group 0), two 32KB rounds (q-half 0 then 1),
  // chunk-swizzled rows; staging buffers are dead after the loop.
  float* mO = (float*)&smem[0][0][0];            // 32 KB: 256 rows x 128 B
  float* mL = mO + 256 * 32;                     // 1 KB
  const int mrow = qw * 64 + lane;

  if (g == 1) {
#pragma unroll
    for (int j = 0; j < 8; j++) {
      const int dt = j >> 2, rb = (j & 3) * 4;
      f32x4 c = { oT0[dt][rb], oT0[dt][rb + 1], oT0[dt][rb + 2], oT0[dt][rb + 3] };
      *(f32x4*)((char*)mO + mrow * 128 + ((j ^ (lane & 7)) * 16)) = c;
    }
    mL[mrow] = lsum0;
  }
  __syncthreads();
  if (g == 0) {
#pragma unroll
    for (int j = 0; j < 8; j++) {
      const int dt = j >> 2, rb = (j & 3) * 4;
      const f32x4 c = *(const f32x4*)((char*)mO + mrow * 128 + ((j ^ (lane & 7)) * 16));
#pragma unroll
      for (int rr = 0; rr < 4; rr++) oT0[dt][rb + rr] += c[rr];
    }
    lsum0 += mL[mrow];
  }
  __syncthreads();
  if (g == 1) {
#pragma unroll
    for (int j = 0; j < 8; j++) {
      const int dt = j >> 2, rb = (j & 3) * 4;
      f32x4 c = { oT1[dt][rb], oT1[dt][rb + 1], oT1[dt][rb + 2], oT1[dt][rb + 3] };
      *(f32x4*)((char*)mO + mrow * 128 + ((j ^ (lane & 7)) * 16)) = c;
    }
    mL[mrow] = lsum1;
  }
  __syncthreads();
  if (g == 0) {
#pragma unroll
    for (int j = 0; j < 8; j++) {
      const int dt = j >> 2, rb = (j & 3) * 4;
      const f32x4 c = *(const f32x4*)((char*)mO + mrow * 128 + ((j ^ (lane & 7)) * 16));
#pragma unroll
      for (int rr = 0; rr < 4; rr++) oT1[dt][rb + rr] += c[rr];
    }
    lsum1 += mL[mrow];

    const float inv0 = 1.0f / (lsum0 + 1e-6f);
    const float inv1 = 1.0f / (lsum1 + 1e-6f);
    const int b = bh >> 4, h = bh & 15;
    const int srow = qb * 256 + qw * 64 + l31;   // q-half 0 row
    const size_t base0 = (size_t)(b * S_LEN + srow) * D_MODEL + h * DH;
    const size_t base1 = base0 + (size_t)32 * D_MODEL;
#pragma unroll
    for (int dt = 0; dt < 2; dt++)
#pragma unroll
      for (int rg = 0; rg < 4; rg++) {
        b16x4 o4;
#pragma unroll
        for (int rr = 0; rr < 4; rr++) o4[rr] = (bf16)(oT0[dt][rg * 4 + rr] * inv0);
        *(b16x4*)(AO + base0 + dt * 32 + rg * 8 + hi * 4) = o4;
      }
#pragma unroll
    for (int dt = 0; dt < 2; dt++)
#pragma unroll
      for (int rg = 0; rg < 4; rg++) {
        b16x4 o4;
#pragma unroll
        for (int rr = 0; rr < 4; rr++) o4[rr] = (bf16)(oT1[dt][rg * 4 + rr] * inv1);
        *(b16x4*)(AO + base1 + dt * 32 + rg * 8 + hi * 4) = o4;
      }
  }
}

extern "C" void kernel_launch(void* const* d_in, const int* in_sizes, int n_in,
                              void* d_out, int out_size, void* d_ws, size_t ws_size,
                              hipStream_t stream) {
  const float* x    = (const float*)d_in[0];
  const float* wqkv = (const float*)d_in[1];
  const float* wout = (const float*)d_in[2];
  float* out = (float*)d_out;

  // ws (32 MB): [Q 8MB][K 8MB][VT 8MB][xb 8MB -> AO after gemm_qkv]
  bf16* Q  = (bf16*)d_ws;
  bf16* K  = Q  + (size_t)TOKENS * D_MODEL;
  bf16* VT = K  + (size_t)TOKENS * D_MODEL;
  bf16* xb = VT + (size_t)TOKENS * D_MODEL;
  bf16* AO = xb;                       // xb dead after gemm_qkv
  bf16* wqkvb = (bf16*)d_out;          // d_out dead until gemm_out
  bf16* woutb = Q;                     // Q dead after attn

  convert_kernel<<<dim3(TOKENS * D_MODEL / (256 * 8)), dim3(256), 0, stream>>>(
      x, xb, TOKENS * D_MODEL / 8);
  convert_kernel<<<dim3(3 * D_MODEL * D_MODEL / (256 * 8)), dim3(256), 0, stream>>>(
      wqkv, wqkvb, 3 * D_MODEL * D_MODEL / 8);

  gemm_qkv_kernel<<<dim3(3 * D_MODEL / BN, TOKENS / BM), dim3(256), 0, stream>>>(
      xb, wqkvb, Q, K, VT);

  attn_kernel<<<dim3(BATCH * NH * (S_LEN / 256)), dim3(512), 0, stream>>>(Q, K, VT, AO);

  convert_kernel<<<dim3(D_MODEL * D_MODEL / (256 * 8)), dim3(256), 0, stream>>>(
      wout, woutb, D_MODEL * D_MODEL / 8);

  gemm_out_kernel<<<dim3(D_MODEL / BN, TOKENS / BM), dim3(256), 0, stream>>>(
      AO, woutb, out);
}